// Round 14
// baseline (88.021 us; speedup 1.0000x reference)
//
#include <hip/hip_runtime.h>
#include <hip/hip_bf16.h>

typedef unsigned int uint32;
typedef __attribute__((ext_vector_type(8))) short    bf16x8;
typedef __attribute__((ext_vector_type(4))) float    f32x4;
typedef __attribute__((ext_vector_type(8))) _Float16 f16x8;
typedef __attribute__((ext_vector_type(4))) _Float16 f16x4;
typedef __attribute__((ext_vector_type(2))) _Float16 f16x2;

#define MFMA_BF(A, B, C) __builtin_amdgcn_mfma_f32_16x16x32_bf16(A, B, C, 0, 0, 0)
#define MFMA_F16(A, B, C) __builtin_amdgcn_mfma_f32_16x16x32_f16(A, B, C, 0, 0, 0)

union FragU { uint32 u[4]; bf16x8 v; };
union H8    { f16x2 h[4]; f16x8 v; };

// 3-pass split (phase-1 z only): hi=trunc top16, lo=bf16(x-hi)
__device__ __forceinline__ void split8(f32x4 a, f32x4 b, bf16x8& hi, bf16x8& lo) {
    float e[8] = {a[0], a[1], a[2], a[3], b[0], b[1], b[2], b[3]};
    FragU H, L;
    #pragma unroll
    for (int q = 0; q < 4; ++q) {
        uint32 u0 = __float_as_uint(e[2*q]);
        uint32 u1 = __float_as_uint(e[2*q + 1]);
        uint32 h0 = u0 & 0xFFFF0000u;
        uint32 h1 = u1 & 0xFFFF0000u;
        float l0 = e[2*q]     - __uint_as_float(h0);
        float l1 = e[2*q + 1] - __uint_as_float(h1);
        H.u[q] = (h0 >> 16) | h1;
        L.u[q] = (__float_as_uint(l0) >> 16) | (__float_as_uint(l1) & 0xFFFF0000u);
    }
    hi = H.v; lo = L.v;
}

// ---- pre-kernel: |Wp| -> bf16 hi/lo; W2 -> fp16; W1,b1 -> packed f16x2 ----
__global__ __launch_bounds__(256) void split_weights(
    const float* __restrict__ Wp, const float* __restrict__ W2,
    const float* __restrict__ W1, const float* __restrict__ b1,
    __hip_bfloat16* __restrict__ wp_hi, __hip_bfloat16* __restrict__ wp_lo,
    _Float16* __restrict__ w2h, f16x2* __restrict__ w1p, f16x2* __restrict__ b1p)
{
    const int i = blockIdx.x * 256 + threadIdx.x;
    if (i < 128 * 64) {
        float x = fabsf(Wp[i]);
        __hip_bfloat16 h = __float2bfloat16(x);          // RNE
        wp_hi[i] = h;
        wp_lo[i] = __float2bfloat16(x - __bfloat162float(h));
    }
    if (i < 128 * 1024) {
        w2h[i] = (_Float16)W2[i];                        // RNE
    }
    if (i < 128 * 16) {
        const int d = i >> 4, q = i & 15;
        f16x2 a, b;
        a[0] = (_Float16)W1[d*32 + 2*q];  a[1] = (_Float16)W1[d*32 + 2*q + 1];
        b[0] = (_Float16)b1[d*32 + 2*q];  b[1] = (_Float16)b1[d*32 + 2*q + 1];
        w1p[i] = a;  b1p[i] = b;
    }
}

// 256 thr = 4 INDEPENDENT waves (no barriers: each wave only touches Y[wv]).
// Y staged as f16 (y is cast to f16 before layer1 anyway -> identical math).
// LDS 18.4 KB/block -> 8 blocks/CU -> 32 waves/CU (2x round-13 occupancy).
// Stride 36 f16 = 72B rows: 8B-aligned f16x4, conflict-free column access
// (18*row mod 32 distinct for row 0..15).
__global__ __launch_bounds__(256, 8) void decoder_mfma(
    const float* __restrict__ z,
    const __hip_bfloat16* __restrict__ wp_hi, const __hip_bfloat16* __restrict__ wp_lo,
    const _Float16* __restrict__ w2h,
    const f16x2* __restrict__ w1p, const f16x2* __restrict__ b1p,
    const float* __restrict__ b2,
    const float* __restrict__ W3, const float* __restrict__ b3,
    float* __restrict__ out)
{
    __shared__ __align__(16) _Float16 Y[4][64][36];   // 18432 B

    const int t    = threadIdx.x;
    const int lane = t & 63;
    const int wv   = __builtin_amdgcn_readfirstlane(t >> 6);  // wave = feature group
    const int l15  = lane & 15;
    const int lg   = lane >> 4;
    const int n0   = blockIdx.x * 64;

    // ---------------- Phase 1: Y = z @ |Wp|^T (3-pass bf16) ---------------
    bf16x8 wh[2][2], wl[2][2];
    #pragma unroll
    for (int dt = 0; dt < 2; ++dt) {
        const int d = wv*32 + dt*16 + l15;
        #pragma unroll
        for (int kt = 0; kt < 2; ++kt) {
            const int off = d*64 + kt*32 + lg*8;
            wh[dt][kt] = *(const bf16x8*)(wp_hi + off);
            wl[dt][kt] = *(const bf16x8*)(wp_lo + off);
        }
    }
    #pragma unroll
    for (int nt = 0; nt < 4; ++nt) {
        bf16x8 zh[2], zl[2];
        #pragma unroll
        for (int kt = 0; kt < 2; ++kt) {
            const float* p = z + (size_t)(n0 + nt*16 + l15)*64 + kt*32 + lg*8;
            split8(*(const f32x4*)p, *(const f32x4*)(p + 4), zh[kt], zl[kt]);
        }
        #pragma unroll
        for (int dt = 0; dt < 2; ++dt) {
            f32x4 acc = {0.f, 0.f, 0.f, 0.f};
            #pragma unroll
            for (int kt = 0; kt < 2; ++kt) {
                acc = MFMA_BF(zh[kt], wh[dt][kt], acc);   // hi*hi
                acc = MFMA_BF(zl[kt], wh[dt][kt], acc);   // lo*hi
                acc = MFMA_BF(zh[kt], wl[dt][kt], acc);   // hi*lo
            }
            #pragma unroll
            for (int r = 0; r < 4; ++r)
                Y[wv][nt*16 + lg*4 + r][dt*16 + l15] = (_Float16)acc[r];
        }
    }
    // no __syncthreads: intra-wave LDS ordering via lgkmcnt (compiler-inserted)

    // ---------------- Phase 2: per-feature tiny MLP (fp16 datapath) -------
    const f16x2 zero2 = {(_Float16)0.f, (_Float16)0.f};
    #pragma unroll 4
    for (int j = 0; j < 32; ++j) {
        const int d = wv*32 + j;                 // wave-uniform feature
        const f16x8 ah0 = *(const f16x8*)(w2h + d*1024 + l15*32 + lg*8);
        const f16x8 ah1 = *(const f16x8*)(w2h + d*1024 + (16 + l15)*32 + lg*8);
        H8 w1u, b1u;
        w1u.v = *(const f16x8*)(w1p + d*16 + lg*4);
        b1u.v = *(const f16x8*)(b1p + d*16 + lg*4);
        const f32x4 b2a = *(const f32x4*)(b2 + d*32 + lg*4);        // k2 = lg*4+r
        const f32x4 b2b = *(const f32x4*)(b2 + d*32 + 16 + lg*4);
        const f32x4 w3a = *(const f32x4*)(W3 + d*32 + lg*4);
        const f32x4 w3b = *(const f32x4*)(W3 + d*32 + 16 + lg*4);
        const float b3v = b3[d];

        // ---- 4 y reads (f16, conflict-free, lg-broadcast) ----
        _Float16 yv[4];
        #pragma unroll
        for (int ct = 0; ct < 4; ++ct) yv[ct] = Y[wv][ct*16 + l15][j];

        // ---- 4 independent packed-fp16 layer1 chains ----
        f16x8 pk[4];
        #pragma unroll
        for (int ct = 0; ct < 4; ++ct) {
            const f16x2 y2 = {yv[ct], yv[ct]};
            H8 u;
            #pragma unroll
            for (int q = 0; q < 4; ++q)
                u.h[q] = __builtin_elementwise_max(
                             __builtin_elementwise_fma(y2, w1u.h[q], b1u.h[q]),
                             zero2);
            pk[ct] = u.v;
        }

        // ---- 8 f16 MFMAs (acc init = b2) ----
        f32x4 A0[4], A1[4];
        #pragma unroll
        for (int ct = 0; ct < 4; ++ct) { A0[ct] = b2a; A1[ct] = b2b; }
        #pragma unroll
        for (int ct = 0; ct < 4; ++ct) {
            A0[ct] = MFMA_F16(ah0, pk[ct], A0[ct]);
            A1[ct] = MFMA_F16(ah1, pk[ct], A1[ct]);
        }

        // ---- 4 independent layer3 tails ----
        #pragma unroll
        for (int ct = 0; ct < 4; ++ct) {
            float s = fmaxf(A0[ct][0], 0.f) * w3a[0];
            s = fmaf(fmaxf(A0[ct][1], 0.f), w3a[1], s);
            s = fmaf(fmaxf(A0[ct][2], 0.f), w3a[2], s);
            s = fmaf(fmaxf(A0[ct][3], 0.f), w3a[3], s);
            s = fmaf(fmaxf(A1[ct][0], 0.f), w3b[0], s);
            s = fmaf(fmaxf(A1[ct][1], 0.f), w3b[1], s);
            s = fmaf(fmaxf(A1[ct][2], 0.f), w3b[2], s);
            s = fmaf(fmaxf(A1[ct][3], 0.f), w3b[3], s);
            s += __shfl_xor(s, 16);      // reduce over the 4 lg groups
            s += __shfl_xor(s, 32);
            const float x = fabsf(s + b3v);
            if (lane < 16) Y[wv][ct*16 + lane][j] = (_Float16)x;  // f16 staging
        }
    }

    // ---------------- coalesced copy-out (f16 -> f32) ---------------------
    const int cg = lane & 7;
    #pragma unroll
    for (int it = 0; it < 8; ++it) {
        const int n = it*8 + (lane >> 3);
        const f16x4 h = *(const f16x4*)&Y[wv][n][cg*4];
        f32x4 v;
        #pragma unroll
        for (int c = 0; c < 4; ++c) v[c] = (float)h[c];
        *(f32x4*)(out + (size_t)(n0 + n)*128 + wv*32 + cg*4) = v;
    }
}

extern "C" void kernel_launch(void* const* d_in, const int* in_sizes, int n_in,
                              void* d_out, int out_size, void* d_ws, size_t ws_size,
                              hipStream_t stream) {
    const float* z  = (const float*)d_in[0];
    const float* Wp = (const float*)d_in[1];
    const float* W1 = (const float*)d_in[2];
    const float* b1 = (const float*)d_in[3];
    const float* W2 = (const float*)d_in[4];
    const float* b2 = (const float*)d_in[5];
    const float* W3 = (const float*)d_in[6];
    const float* b3 = (const float*)d_in[7];
    float* out = (float*)d_out;

    __hip_bfloat16* wp_hi = (__hip_bfloat16*)d_ws;          // 8192 B
    __hip_bfloat16* wp_lo = wp_hi + 128 * 64;               // 8192 B
    _Float16*       w2h   = (_Float16*)(wp_lo + 128 * 64);  // 262144 B
    f16x2*          w1p   = (f16x2*)(w2h + 128 * 1024);     // 4096 B
    f16x2*          b1p   = w1p + 128 * 16;                 // 4096 B

    hipLaunchKernelGGL(split_weights, dim3(512), dim3(256), 0, stream,
                       Wp, W2, W1, b1, wp_hi, wp_lo, w2h, w1p, b1p);
    hipLaunchKernelGGL(decoder_mfma, dim3(1024), dim3(256), 0, stream,
                       z, wp_hi, wp_lo, w2h, w1p, b1p, b2, W3, b3, out);
}

// Round 15
// 71.674 us; speedup vs baseline: 1.2281x; 1.2281x over previous
//
#include <hip/hip_runtime.h>
#include <hip/hip_bf16.h>

typedef unsigned int uint32;
typedef __attribute__((ext_vector_type(8))) short    bf16x8;
typedef __attribute__((ext_vector_type(4))) float    f32x4;
typedef __attribute__((ext_vector_type(8))) _Float16 f16x8;
typedef __attribute__((ext_vector_type(4))) _Float16 f16x4;
typedef __attribute__((ext_vector_type(2))) _Float16 f16x2;

#define MFMA_BF(A, B, C) __builtin_amdgcn_mfma_f32_16x16x32_bf16(A, B, C, 0, 0, 0)
#define MFMA_F16(A, B, C) __builtin_amdgcn_mfma_f32_16x16x32_f16(A, B, C, 0, 0, 0)

union FragU { uint32 u[4]; bf16x8 v; };
union H8    { f16x2 h[4]; f16x8 v; };

// 3-pass split (phase-1 z only): hi=trunc top16, lo=bf16(x-hi)
__device__ __forceinline__ void split8(f32x4 a, f32x4 b, bf16x8& hi, bf16x8& lo) {
    float e[8] = {a[0], a[1], a[2], a[3], b[0], b[1], b[2], b[3]};
    FragU H, L;
    #pragma unroll
    for (int q = 0; q < 4; ++q) {
        uint32 u0 = __float_as_uint(e[2*q]);
        uint32 u1 = __float_as_uint(e[2*q + 1]);
        uint32 h0 = u0 & 0xFFFF0000u;
        uint32 h1 = u1 & 0xFFFF0000u;
        float l0 = e[2*q]     - __uint_as_float(h0);
        float l1 = e[2*q + 1] - __uint_as_float(h1);
        H.u[q] = (h0 >> 16) | h1;
        L.u[q] = (__float_as_uint(l0) >> 16) | (__float_as_uint(l1) & 0xFFFF0000u);
    }
    hi = H.v; lo = L.v;
}

// ---- pre-kernel: |Wp| -> bf16 hi/lo; W2 -> fp16; W1,b1 -> packed f16x2 ----
__global__ __launch_bounds__(256) void split_weights(
    const float* __restrict__ Wp, const float* __restrict__ W2,
    const float* __restrict__ W1, const float* __restrict__ b1,
    __hip_bfloat16* __restrict__ wp_hi, __hip_bfloat16* __restrict__ wp_lo,
    _Float16* __restrict__ w2h, f16x2* __restrict__ w1p, f16x2* __restrict__ b1p)
{
    const int i = blockIdx.x * 256 + threadIdx.x;
    if (i < 128 * 64) {
        float x = fabsf(Wp[i]);
        __hip_bfloat16 h = __float2bfloat16(x);          // RNE
        wp_hi[i] = h;
        wp_lo[i] = __float2bfloat16(x - __bfloat162float(h));
    }
    if (i < 128 * 1024) {
        w2h[i] = (_Float16)W2[i];                        // RNE
    }
    if (i < 128 * 16) {
        const int d = i >> 4, q = i & 15;
        f16x2 a, b;
        a[0] = (_Float16)W1[d*32 + 2*q];  a[1] = (_Float16)W1[d*32 + 2*q + 1];
        b[0] = (_Float16)b1[d*32 + 2*q];  b[1] = (_Float16)b1[d*32 + 2*q + 1];
        w1p[i] = a;  b1p[i] = b;
    }
}

// 256 thr = 4 INDEPENDENT waves (no barriers). Block = 64 samples x 64
// features (bid&1 selects which 64-feature half); wave wv owns 16 features.
// Grid 2048 x 4 waves = 8192 waves = 100% of device wave slots.
// LDS 9.2 KB f16 -> 8+ blocks/CU; launch_bounds(256,4) keeps VGPR ~48-64
// (r14's (256,8) crushed VGPR to 32 -> spills; r14's 1024-block grid capped
// occupancy at 50% -- both fixed here).
__global__ __launch_bounds__(256, 4) void decoder_mfma(
    const float* __restrict__ z,
    const __hip_bfloat16* __restrict__ wp_hi, const __hip_bfloat16* __restrict__ wp_lo,
    const _Float16* __restrict__ w2h,
    const f16x2* __restrict__ w1p, const f16x2* __restrict__ b1p,
    const float* __restrict__ b2,
    const float* __restrict__ W3, const float* __restrict__ b3,
    float* __restrict__ out)
{
    __shared__ __align__(16) _Float16 Y[4][64][18];   // 9216 B

    const int t    = threadIdx.x;
    const int lane = t & 63;
    const int wv   = __builtin_amdgcn_readfirstlane(t >> 6);
    const int l15  = lane & 15;
    const int lg   = lane >> 4;
    const int dbase = (blockIdx.x & 1) * 64 + wv * 16;   // this wave's features
    const int n0    = (blockIdx.x >> 1) * 64;            // sample tile

    // ---------------- Phase 1: Y = z @ |Wp|^T (3-pass bf16) ---------------
    bf16x8 wh[2], wl[2];
    #pragma unroll
    for (int kt = 0; kt < 2; ++kt) {
        const int off = (dbase + l15)*64 + kt*32 + lg*8;
        wh[kt] = *(const bf16x8*)(wp_hi + off);
        wl[kt] = *(const bf16x8*)(wp_lo + off);
    }
    #pragma unroll
    for (int nt = 0; nt < 4; ++nt) {
        bf16x8 zh[2], zl[2];
        #pragma unroll
        for (int kt = 0; kt < 2; ++kt) {
            const float* p = z + (size_t)(n0 + nt*16 + l15)*64 + kt*32 + lg*8;
            split8(*(const f32x4*)p, *(const f32x4*)(p + 4), zh[kt], zl[kt]);
        }
        f32x4 acc = {0.f, 0.f, 0.f, 0.f};
        #pragma unroll
        for (int kt = 0; kt < 2; ++kt) {
            acc = MFMA_BF(zh[kt], wh[kt], acc);   // hi*hi
            acc = MFMA_BF(zl[kt], wh[kt], acc);   // lo*hi
            acc = MFMA_BF(zh[kt], wl[kt], acc);   // hi*lo
        }
        #pragma unroll
        for (int r = 0; r < 4; ++r)
            Y[wv][nt*16 + lg*4 + r][l15] = (_Float16)acc[r];
    }
    // no __syncthreads: each wave only touches Y[wv]; intra-wave lgkmcnt orders

    // ---------------- Phase 2: per-feature tiny MLP (fp16 datapath) -------
    const f16x2 zero2 = {(_Float16)0.f, (_Float16)0.f};
    #pragma unroll 4
    for (int j = 0; j < 16; ++j) {
        const int d = dbase + j;                 // wave-uniform feature
        const f16x8 ah0 = *(const f16x8*)(w2h + d*1024 + l15*32 + lg*8);
        const f16x8 ah1 = *(const f16x8*)(w2h + d*1024 + (16 + l15)*32 + lg*8);
        H8 w1u, b1u;
        w1u.v = *(const f16x8*)(w1p + d*16 + lg*4);
        b1u.v = *(const f16x8*)(b1p + d*16 + lg*4);
        const f32x4 b2a = *(const f32x4*)(b2 + d*32 + lg*4);        // k2 = lg*4+r
        const f32x4 b2b = *(const f32x4*)(b2 + d*32 + 16 + lg*4);
        const f32x4 w3a = *(const f32x4*)(W3 + d*32 + lg*4);
        const f32x4 w3b = *(const f32x4*)(W3 + d*32 + 16 + lg*4);
        const float b3v = b3[d];

        // ---- 4 y reads (f16, conflict-free: bank = (9*row + j/2)%32) ----
        _Float16 yv[4];
        #pragma unroll
        for (int ct = 0; ct < 4; ++ct) yv[ct] = Y[wv][ct*16 + l15][j];

        // ---- 4 independent packed-fp16 layer1 chains ----
        f16x8 pk[4];
        #pragma unroll
        for (int ct = 0; ct < 4; ++ct) {
            const f16x2 y2 = {yv[ct], yv[ct]};
            H8 u;
            #pragma unroll
            for (int q = 0; q < 4; ++q)
                u.h[q] = __builtin_elementwise_max(
                             __builtin_elementwise_fma(y2, w1u.h[q], b1u.h[q]),
                             zero2);
            pk[ct] = u.v;
        }

        // ---- 8 f16 MFMAs (acc init = b2) ----
        f32x4 A0[4], A1[4];
        #pragma unroll
        for (int ct = 0; ct < 4; ++ct) { A0[ct] = b2a; A1[ct] = b2b; }
        #pragma unroll
        for (int ct = 0; ct < 4; ++ct) {
            A0[ct] = MFMA_F16(ah0, pk[ct], A0[ct]);
            A1[ct] = MFMA_F16(ah1, pk[ct], A1[ct]);
        }

        // ---- 4 independent layer3 tails ----
        #pragma unroll
        for (int ct = 0; ct < 4; ++ct) {
            float s = fmaxf(A0[ct][0], 0.f) * w3a[0];
            s = fmaf(fmaxf(A0[ct][1], 0.f), w3a[1], s);
            s = fmaf(fmaxf(A0[ct][2], 0.f), w3a[2], s);
            s = fmaf(fmaxf(A0[ct][3], 0.f), w3a[3], s);
            s = fmaf(fmaxf(A1[ct][0], 0.f), w3b[0], s);
            s = fmaf(fmaxf(A1[ct][1], 0.f), w3b[1], s);
            s = fmaf(fmaxf(A1[ct][2], 0.f), w3b[2], s);
            s = fmaf(fmaxf(A1[ct][3], 0.f), w3b[3], s);
            s += __shfl_xor(s, 16);      // reduce over the 4 lg groups
            s += __shfl_xor(s, 32);
            const float x = fabsf(s + b3v);
            if (lane < 16) Y[wv][ct*16 + lane][j] = (_Float16)x;  // f16 staging
        }
    }

    // ---------------- coalesced copy-out (f16 -> f32) ---------------------
    // wave tile = 64 rows x 16 cols; per iter 16 rows, 4 lanes x 16B per row.
    const int cq = lane & 3;          // 4-float chunk within the 16 features
    const int rw = lane >> 2;         // 16 rows per iteration
    #pragma unroll
    for (int it = 0; it < 4; ++it) {
        const int n = it*16 + rw;
        const f16x4 h = *(const f16x4*)&Y[wv][n][cq*4];
        f32x4 v;
        #pragma unroll
        for (int c = 0; c < 4; ++c) v[c] = (float)h[c];
        *(f32x4*)(out + (size_t)(n0 + n)*128 + dbase + cq*4) = v;
    }
}

extern "C" void kernel_launch(void* const* d_in, const int* in_sizes, int n_in,
                              void* d_out, int out_size, void* d_ws, size_t ws_size,
                              hipStream_t stream) {
    const float* z  = (const float*)d_in[0];
    const float* Wp = (const float*)d_in[1];
    const float* W1 = (const float*)d_in[2];
    const float* b1 = (const float*)d_in[3];
    const float* W2 = (const float*)d_in[4];
    const float* b2 = (const float*)d_in[5];
    const float* W3 = (const float*)d_in[6];
    const float* b3 = (const float*)d_in[7];
    float* out = (float*)d_out;

    __hip_bfloat16* wp_hi = (__hip_bfloat16*)d_ws;          // 8192 B
    __hip_bfloat16* wp_lo = wp_hi + 128 * 64;               // 8192 B
    _Float16*       w2h   = (_Float16*)(wp_lo + 128 * 64);  // 262144 B
    f16x2*          w1p   = (f16x2*)(w2h + 128 * 1024);     // 4096 B
    f16x2*          b1p   = w1p + 128 * 16;                 // 4096 B

    hipLaunchKernelGGL(split_weights, dim3(512), dim3(256), 0, stream,
                       Wp, W2, W1, b1, wp_hi, wp_lo, w2h, w1p, b1p);
    // 2048 blocks: bid&1 = feature half, bid>>1 = sample tile
    hipLaunchKernelGGL(decoder_mfma, dim3(2048), dim3(256), 0, stream,
                       z, wp_hi, wp_lo, w2h, w1p, b1p, b2, W3, b3, out);
}

// Round 16
// 70.290 us; speedup vs baseline: 1.2523x; 1.0197x over previous
//
#include <hip/hip_runtime.h>
#include <hip/hip_bf16.h>

typedef unsigned int uint32;
typedef __attribute__((ext_vector_type(8))) short    bf16x8;
typedef __attribute__((ext_vector_type(4))) float    f32x4;
typedef __attribute__((ext_vector_type(8))) _Float16 f16x8;
typedef __attribute__((ext_vector_type(4))) _Float16 f16x4;
typedef __attribute__((ext_vector_type(2))) _Float16 f16x2;

#define MFMA_BF(A, B, C) __builtin_amdgcn_mfma_f32_16x16x32_bf16(A, B, C, 0, 0, 0)
#define MFMA_F16(A, B, C) __builtin_amdgcn_mfma_f32_16x16x32_f16(A, B, C, 0, 0, 0)

union FragU { uint32 u[4]; bf16x8 v; };
union H8    { f16x2 h[4]; f16x8 v; };

// 3-pass split (phase-1 z only): hi=trunc top16, lo=bf16(x-hi)
__device__ __forceinline__ void split8(f32x4 a, f32x4 b, bf16x8& hi, bf16x8& lo) {
    float e[8] = {a[0], a[1], a[2], a[3], b[0], b[1], b[2], b[3]};
    FragU H, L;
    #pragma unroll
    for (int q = 0; q < 4; ++q) {
        uint32 u0 = __float_as_uint(e[2*q]);
        uint32 u1 = __float_as_uint(e[2*q + 1]);
        uint32 h0 = u0 & 0xFFFF0000u;
        uint32 h1 = u1 & 0xFFFF0000u;
        float l0 = e[2*q]     - __uint_as_float(h0);
        float l1 = e[2*q + 1] - __uint_as_float(h1);
        H.u[q] = (h0 >> 16) | h1;
        L.u[q] = (__float_as_uint(l0) >> 16) | (__float_as_uint(l1) & 0xFFFF0000u);
    }
    hi = H.v; lo = L.v;
}

// ---- pre-kernel: |Wp| -> bf16 hi/lo; W2 -> fp16; W1,b1 -> packed f16x2 ----
__global__ __launch_bounds__(256) void split_weights(
    const float* __restrict__ Wp, const float* __restrict__ W2,
    const float* __restrict__ W1, const float* __restrict__ b1,
    __hip_bfloat16* __restrict__ wp_hi, __hip_bfloat16* __restrict__ wp_lo,
    _Float16* __restrict__ w2h, f16x2* __restrict__ w1p, f16x2* __restrict__ b1p)
{
    const int i = blockIdx.x * 256 + threadIdx.x;
    if (i < 128 * 64) {
        float x = fabsf(Wp[i]);
        __hip_bfloat16 h = __float2bfloat16(x);          // RNE
        wp_hi[i] = h;
        wp_lo[i] = __float2bfloat16(x - __bfloat162float(h));
    }
    if (i < 128 * 1024) {
        w2h[i] = (_Float16)W2[i];                        // RNE
    }
    if (i < 128 * 16) {
        const int d = i >> 4, q = i & 15;
        f16x2 a, b;
        a[0] = (_Float16)W1[d*32 + 2*q];  a[1] = (_Float16)W1[d*32 + 2*q + 1];
        b[0] = (_Float16)b1[d*32 + 2*q];  b[1] = (_Float16)b1[d*32 + 2*q + 1];
        w1p[i] = a;  b1p[i] = b;
    }
}

// 1 wave per block: 128 SAMPLES x 16 features. Per-j weight loads (the
// dominant latency stall -- hipcc won't hoist them, r7/r11/r15) amortize
// over 2x the samples of r13. Per j: load weights ONCE, run the r13 body
// twice (h = 0/1, 64 samples each) -> peak VGPR ~90, stays 4 waves/SIMD.
// Y staged f16 [128][20]: row = 40B = 10 dwords -> 16 rows hit 16 distinct
// banks (10r mod 32 distinct), conflict-free column reads.
__global__ __launch_bounds__(64, 4) void decoder_mfma(
    const float* __restrict__ z,
    const __hip_bfloat16* __restrict__ wp_hi, const __hip_bfloat16* __restrict__ wp_lo,
    const _Float16* __restrict__ w2h,
    const f16x2* __restrict__ w1p, const f16x2* __restrict__ b1p,
    const float* __restrict__ b2,
    const float* __restrict__ W3, const float* __restrict__ b3,
    float* __restrict__ out)
{
    __shared__ __align__(16) _Float16 Y[128][20];   // 5120 B

    const int lane = threadIdx.x;    // 0..63
    const int l15  = lane & 15;
    const int lg   = lane >> 4;
    const int g     = blockIdx.x & 7;            // feature group: 16 features
    const int dbase = g * 16;
    const int n0    = (blockIdx.x >> 3) * 128;   // sample tile

    // ---------------- Phase 1: Y = z @ |Wp|^T (3-pass bf16) ---------------
    bf16x8 wh[2], wl[2];
    #pragma unroll
    for (int kt = 0; kt < 2; ++kt) {
        const int off = (dbase + l15)*64 + kt*32 + lg*8;
        wh[kt] = *(const bf16x8*)(wp_hi + off);
        wl[kt] = *(const bf16x8*)(wp_lo + off);
    }
    #pragma unroll
    for (int nt = 0; nt < 8; ++nt) {
        bf16x8 zh[2], zl[2];
        #pragma unroll
        for (int kt = 0; kt < 2; ++kt) {
            const float* p = z + (size_t)(n0 + nt*16 + l15)*64 + kt*32 + lg*8;
            split8(*(const f32x4*)p, *(const f32x4*)(p + 4), zh[kt], zl[kt]);
        }
        f32x4 acc = {0.f, 0.f, 0.f, 0.f};
        #pragma unroll
        for (int kt = 0; kt < 2; ++kt) {
            acc = MFMA_BF(zh[kt], wh[kt], acc);   // hi*hi
            acc = MFMA_BF(zl[kt], wh[kt], acc);   // lo*hi
            acc = MFMA_BF(zh[kt], wl[kt], acc);   // hi*lo
        }
        #pragma unroll
        for (int r = 0; r < 4; ++r)
            Y[nt*16 + lg*4 + r][l15] = (_Float16)acc[r];
    }
    // single wave: intra-wave lgkmcnt ordering suffices, no barrier

    // ---------------- Phase 2: per-feature tiny MLP (fp16 datapath) -------
    const f16x2 zero2 = {(_Float16)0.f, (_Float16)0.f};
    #pragma unroll 2
    for (int j = 0; j < 16; ++j) {
        const int d = dbase + j;                 // wave-uniform feature
        // weights loaded ONCE per j, used for 128 samples
        const f16x8 ah0 = *(const f16x8*)(w2h + d*1024 + l15*32 + lg*8);
        const f16x8 ah1 = *(const f16x8*)(w2h + d*1024 + (16 + l15)*32 + lg*8);
        H8 w1u, b1u;
        w1u.v = *(const f16x8*)(w1p + d*16 + lg*4);
        b1u.v = *(const f16x8*)(b1p + d*16 + lg*4);
        const f32x4 b2a = *(const f32x4*)(b2 + d*32 + lg*4);        // k2 = lg*4+r
        const f32x4 b2b = *(const f32x4*)(b2 + d*32 + 16 + lg*4);
        const f32x4 w3a = *(const f32x4*)(W3 + d*32 + lg*4);
        const f32x4 w3b = *(const f32x4*)(W3 + d*32 + 16 + lg*4);
        const float b3v = b3[d];

        #pragma unroll
        for (int h = 0; h < 2; ++h) {            // two 64-sample halves
            const int nb = h * 64;

            _Float16 yv[4];
            #pragma unroll
            for (int ct = 0; ct < 4; ++ct) yv[ct] = Y[nb + ct*16 + l15][j];

            f16x8 pk[4];
            #pragma unroll
            for (int ct = 0; ct < 4; ++ct) {
                const f16x2 y2 = {yv[ct], yv[ct]};
                H8 u;
                #pragma unroll
                for (int q = 0; q < 4; ++q)
                    u.h[q] = __builtin_elementwise_max(
                                 __builtin_elementwise_fma(y2, w1u.h[q], b1u.h[q]),
                                 zero2);
                pk[ct] = u.v;
            }

            f32x4 A0[4], A1[4];
            #pragma unroll
            for (int ct = 0; ct < 4; ++ct) { A0[ct] = b2a; A1[ct] = b2b; }
            #pragma unroll
            for (int ct = 0; ct < 4; ++ct) {
                A0[ct] = MFMA_F16(ah0, pk[ct], A0[ct]);
                A1[ct] = MFMA_F16(ah1, pk[ct], A1[ct]);
            }

            #pragma unroll
            for (int ct = 0; ct < 4; ++ct) {
                float s = fmaxf(A0[ct][0], 0.f) * w3a[0];
                s = fmaf(fmaxf(A0[ct][1], 0.f), w3a[1], s);
                s = fmaf(fmaxf(A0[ct][2], 0.f), w3a[2], s);
                s = fmaf(fmaxf(A0[ct][3], 0.f), w3a[3], s);
                s = fmaf(fmaxf(A1[ct][0], 0.f), w3b[0], s);
                s = fmaf(fmaxf(A1[ct][1], 0.f), w3b[1], s);
                s = fmaf(fmaxf(A1[ct][2], 0.f), w3b[2], s);
                s = fmaf(fmaxf(A1[ct][3], 0.f), w3b[3], s);
                s += __shfl_xor(s, 16);      // reduce over the 4 lg groups
                s += __shfl_xor(s, 32);
                const float x = fabsf(s + b3v);
                if (lane < 16) Y[nb + ct*16 + lane][j] = (_Float16)x;
            }
        }
    }

    // ---------------- coalesced copy-out (f16 -> f32) ---------------------
    // 128 rows x 16 cols; per iter: 16 rows, 4 lanes x 16B-out per row.
    const int cq = lane & 3;
    const int rw = lane >> 2;
    #pragma unroll
    for (int it = 0; it < 8; ++it) {
        const int n = it*16 + rw;
        const f16x4 hh = *(const f16x4*)&Y[n][cq*4];
        f32x4 v;
        #pragma unroll
        for (int c = 0; c < 4; ++c) v[c] = (float)hh[c];
        *(f32x4*)(out + (size_t)(n0 + n)*128 + dbase + cq*4) = v;
    }
}

extern "C" void kernel_launch(void* const* d_in, const int* in_sizes, int n_in,
                              void* d_out, int out_size, void* d_ws, size_t ws_size,
                              hipStream_t stream) {
    const float* z  = (const float*)d_in[0];
    const float* Wp = (const float*)d_in[1];
    const float* W1 = (const float*)d_in[2];
    const float* b1 = (const float*)d_in[3];
    const float* W2 = (const float*)d_in[4];
    const float* b2 = (const float*)d_in[5];
    const float* W3 = (const float*)d_in[6];
    const float* b3 = (const float*)d_in[7];
    float* out = (float*)d_out;

    __hip_bfloat16* wp_hi = (__hip_bfloat16*)d_ws;          // 8192 B
    __hip_bfloat16* wp_lo = wp_hi + 128 * 64;               // 8192 B
    _Float16*       w2h   = (_Float16*)(wp_lo + 128 * 64);  // 262144 B
    f16x2*          w1p   = (f16x2*)(w2h + 128 * 1024);     // 4096 B
    f16x2*          b1p   = w1p + 128 * 16;                 // 4096 B

    hipLaunchKernelGGL(split_weights, dim3(512), dim3(256), 0, stream,
                       Wp, W2, W1, b1, wp_hi, wp_lo, w2h, w1p, b1p);
    // 4096 one-wave blocks: bid&7 = feature group, bid>>3 = 128-sample tile
    hipLaunchKernelGGL(decoder_mfma, dim3(4096), dim3(64), 0, stream,
                       z, wp_hi, wp_lo, w2h, w1p, b1p, b2, W3, b3, out);
}